// Round 11
// baseline (107.795 us; speedup 1.0000x reference)
//
#include <hip/hip_runtime.h>

// ContrastiveLoss on MI355X (gfx950), B=8192, D=128, labels in [0,2048).
// loss = -(1/cnt) sum_{i: P_i>0} [ S_i/P_i - M - ln Z_i ]
//   Z_i = sum_{j != i} exp(sim_ij - M),  sim = E E^T / T,  M = 1/T (valid shift).
//   S_i = (e_i . g_{lab_i} - e_i . e_i) / T  with fp32 class sums g_c.
//   P_i = count[lab_i] - 1.
// R22: R21 (91.2us best) + fin2 folded into fin1 WITHOUT the R14 fence:
//      per-block atomicAdd(gtot/gcnt) [device-scope, memory-side-coherent,
//      no L2 writeback needed] -> s_waitcnt vmcnt(0) [wave-local ordering of
//      the adds before the ticket, NOT a cache flush] -> ticket atomicAdd;
//      the last block atomic-reads both accumulators (atomicAdd(p,0) --
//      coherent read, immune to stale per-XCD L2) and stores the loss.
//      Saves one launch + one graph gap. R14's +9us came from per-block
//      __threadfence (cross-XCD writeback); this path has none.
//      Main kernel UNTOUCHED (frozen: 5 falsified attempts R12/15/16/19/20).
// Retained ledger: R17 8-wave 256x128 tile body (staged B, XOR LDS layout,
//      0 conflicts measured, 16x16x32 MFMA, 32 waves/CU); R18 XCD bijective
//      swizzle + class-sum fused as main blocks [1056,1312) + zpartR[row][tj2]
//      transposed; R21 fin1 TLP x2 + inline sdbf; bf16 Ebf intermediate is
//      L2-residency-critical (R19: fp32 direct = +10us); VGPR must stay <=64
//      in main (R16/R20: occupancy step); plain launch_bounds (R3/R7/R10);
//      no zpartR pre-zero (fin1 masks lane >= 2*(r>>8)).

#define BATCH 8192
#define DIMK  128
#define INV_T 14.285714285714286f
#define MSUB  14.285714285714286f
#define K1    20.609929155311264f   // INV_T * log2(e)
#define K2    20.609929155311264f   // MSUB  * log2(e)

typedef short bf16x8 __attribute__((ext_vector_type(8)));
typedef float f32x4  __attribute__((ext_vector_type(4)));

__device__ __forceinline__ unsigned short f2bf_rne(float f) {
    unsigned u = __float_as_uint(f);
    u += 0x7FFFu + ((u >> 16) & 1u);
    return (unsigned short)(u >> 16);
}
__device__ __forceinline__ float bf2f(unsigned short b) {
    return __uint_as_float(((unsigned)b) << 16);
}

// ---------------------------------------------------------------------------
// Prep: 1024 blocks: fp32->bf16 cvt (4 elems/thread) + zero zcol (32 KB)
//       + zero the finale scalars (gtot/gcntT/ticket; re-zeroed each replay).
__global__ __launch_bounds__(256) void
prep_kernel(const float* __restrict__ emb, ushort* __restrict__ Ebf,
            float4* __restrict__ zcol4, float* __restrict__ gtot,
            int* __restrict__ gcntT, int* __restrict__ ticket) {
    int i = blockIdx.x * 256 + threadIdx.x;
    if (i == 0) { *gtot = 0.f; *gcntT = 0; *ticket = 0; }
    if (i < 2048) {                           // zcol: 8192 floats = 2048 float4
        float4 z = {0.f, 0.f, 0.f, 0.f};
        zcol4[i] = z;
    }
    float4 v = ((const float4*)emb)[i];
    ushort4 o;
    o.x = f2bf_rne(v.x); o.y = f2bf_rne(v.y);
    o.z = f2bf_rne(v.z); o.w = f2bf_rne(v.w);
    ((ushort4*)Ebf)[i] = o;
}

// ---------------------------------------------------------------------------
// Main (FROZEN from R21): blocks [0,1056): Z partials over the upper
// triangle; blocks [1056,1312): class sums (8 classes/block, overlapping
// the tile window). Tile blocks: 1056 = 528 macro-tiles x 2 col-halves,
// 512 threads (8 waves), XCD-swizzled. Macro-tile (ti,tj), tj>=ti; block
// covers rows [ti*256,+256) x cols [tj*256+ch*128,+128). B staged once
// (32 KB), conflict-free XOR layout (measured 0 conflicts):
// chunk (col,c) -> unit (col>>4)*256 + c*16 + ((col&15)^c). Wave owns 32
// rows (afrag[2][4]); single 4-deep MFMA chain per mt (VGPR<=64).
// Row partials -> zpartR[row][tj2] (tj2 = tj*2+ch). Col partials (off-diag
// only) -> cpart LDS combine -> atomicAdd zcol[col].
__global__ __launch_bounds__(512) void
contrastive_main(const ushort* __restrict__ Ebf, float* __restrict__ zpartR,
                 float* __restrict__ zcol, const float* __restrict__ emb,
                 const int* __restrict__ labels, float* __restrict__ gsum,
                 int* __restrict__ gcnt) {
    __shared__ __align__(16) ushort Bs[2048 * 8];     // 32 KB (2048 16B units)
    __shared__ float cpart[8][128];                   // 4 KB
    const int tid  = threadIdx.x;
    const int lane = tid & 63;
    const int wid  = tid >> 6;                        // 0..7
    const int quad = lane >> 4;
    const int l16  = lane & 15;

    if (blockIdx.x >= 1056) {
        // ---- class sums: 256 blocks x 8 waves, 1 class per wave ----
        int* labs = (int*)&Bs[0];                     // alias the 32 KB region
#pragma unroll
        for (int it = 0; it < 4; ++it)
            ((int4*)labs)[it * 512 + tid] = ((const int4*)labels)[it * 512 + tid];
        __syncthreads();

        const int c = (blockIdx.x - 1056) * 8 + wid;  // class id [0,2048)
        float2 acc = {0.f, 0.f};
        int cnt = 0;
        int nl = labs[lane];
        for (int j0 = 0; j0 < BATCH; j0 += 64) {
            int cur = nl;
            int nidx = j0 + 64 < BATCH ? j0 + 64 : 0;
            nl = labs[nidx + lane];
            unsigned long long m = __ballot(cur == c);
            cnt += __popcll(m);
            while (m) {
                int j = __ffsll(m) - 1;
                m &= m - 1;
                float2 v = *(const float2*)(emb + (size_t)(j0 + j) * DIMK + lane * 2);
                acc.x += v.x; acc.y += v.y;
            }
        }
        *(float2*)(gsum + (size_t)c * DIMK + lane * 2) = acc;
        if (lane == 0) gcnt[c] = cnt;
        return;
    }

    // ---- tile path ----
    // XCD-aware bijective swizzle: 1056 = 8 * 132; (bid&7) == XCD gets the
    // contiguous tt range [x*132, x*132+132).
    const int bid = blockIdx.x;
    const int tt  = (bid & 7) * 132 + (bid >> 3);

    // tt -> (ti, tj, ch)
    int b = tt >> 1;
    const int ch = tt & 1;
    int ti = 0;
    while (b >= 32 - ti) { b -= 32 - ti; ++ti; }
    const int tj  = ti + b;
    const int tj2 = tj * 2 + ch;
    const int row_base = ti * 256 + wid * 32;
    const int col_base = tj * 256 + ch * 128;

    // A-fragments for this wave's 32 rows (register-resident), from L2.
    bf16x8 afrag[2][4];
#pragma unroll
    for (int mt = 0; mt < 2; ++mt)
#pragma unroll
        for (int kk = 0; kk < 4; ++kk)
            afrag[mt][kk] = *(const bf16x8*)(Ebf + (size_t)(row_base + mt * 16 + l16) * DIMK
                                             + kk * 32 + quad * 8);

    // Stage 128 cols: 2048 16B chunks; thread t handles chunk f = it*512+t:
    // col = f>>4, c = f&15; global read coalesced (16 lanes = 256B of one col);
    // LDS write at swizzled unit (col>>4)*256 + c*16 + ((col&15)^c).
#pragma unroll
    for (int it = 0; it < 4; ++it) {
        int f   = it * 512 + tid;
        int col = f >> 4;
        int c   = f & 15;
        uint4 v = *(const uint4*)(Ebf + (size_t)(col_base + col) * DIMK + c * 8);
        *(uint4*)&Bs[((col >> 4) * 256 + c * 16 + ((col & 15) ^ c)) * 8] = v;
    }
    __syncthreads();

    float zacc[8];
#pragma unroll
    for (int s = 0; s < 8; ++s) zacc[s] = 0.f;

    for (int nt = 0; nt < 8; ++nt) {
        bf16x8 bfrag[4];
#pragma unroll
        for (int kk = 0; kk < 4; ++kk) {
            const int c2 = kk * 4 + quad;
            bfrag[kk] = *(const bf16x8*)&Bs[(nt * 256 + c2 * 16 + (l16 ^ c2)) * 8];
        }

        float csum = 0.f;
#pragma unroll
        for (int mt = 0; mt < 2; ++mt) {
            f32x4 c = {0.f, 0.f, 0.f, 0.f};
#pragma unroll
            for (int kk = 0; kk < 4; ++kk)
                c = __builtin_amdgcn_mfma_f32_16x16x32_bf16(afrag[mt][kk], bfrag[kk], c, 0, 0, 0);
#pragma unroll
            for (int r = 0; r < 4; ++r) {
                float e = __builtin_amdgcn_exp2f(__builtin_fmaf(c[r], K1, -K2));
                zacc[mt * 4 + r] += e;
                csum += e;
            }
        }
        // col partial for col (nt*16 + l16) over this wave's 32 rows
        csum += __shfl_xor(csum, 16, 64);
        csum += __shfl_xor(csum, 32, 64);
        if (quad == 0) cpart[wid][nt * 16 + l16] = csum;
    }

    // Row partials: reduce each row-slot over the 16 lanes sharing the row;
    // store transposed: zpartR[row][tj2] (fin1 reads 256B/row coalesced).
#pragma unroll
    for (int s = 0; s < 8; ++s) {
        float z = zacc[s];
#pragma unroll
        for (int m = 1; m <= 8; m <<= 1) z += __shfl_xor(z, m, 64);
        if (l16 == 0) {
            int row = row_base + (s >> 2) * 16 + quad * 4 + (s & 3);
            zpartR[(size_t)row * 64 + tj2] = z;
        }
    }

    // Col partials: combine the 8 waves, one distributed atomic per column.
    __syncthreads();
    if (ti != tj && tid < 128) {
        float s = cpart[0][tid] + cpart[1][tid] + cpart[2][tid] + cpart[3][tid]
                + cpart[4][tid] + cpart[5][tid] + cpart[6][tid] + cpart[7][tid];
        atomicAdd(&zcol[col_base + tid], s);
    }
}

// ---------------------------------------------------------------------------
// Finalize: 1024 blocks x 256 (4 waves); each wave processes 2 rows.
// Per row: lane l covers dims 2l,2l+1; Z gather is zpartR[r][lane] — 256B
// contiguous (written only for tj2 >= 2*(r>>8): mask, no pre-zeroing);
// zcol[r] added after the butterfly; bf16 self-dot recomputed inline.
// Tail (R22): per-block atomicAdd into gtot/gcntT; vmcnt(0) orders the adds
// before the ticket RMW (wave-local wait, no cache flush); last block
// atomic-reads the accumulators (coherent by construction) and stores loss.
__global__ __launch_bounds__(256) void
finalize1(const float* __restrict__ emb, const int* __restrict__ labels,
          const float* __restrict__ gsum, const int* __restrict__ gcnt,
          const float* __restrict__ zpartR, const float* __restrict__ zcol,
          float* __restrict__ gtot, int* __restrict__ gcntT,
          int* __restrict__ ticket, float* __restrict__ out) {
    __shared__ float sf[4];
    __shared__ int   si[4];
    const int lane = threadIdx.x & 63;
    const int wid  = threadIdx.x >> 6;

    float wsum = 0.f;
    int   wcnt = 0;
#pragma unroll
    for (int it = 0; it < 2; ++it) {
        const int r   = blockIdx.x * 8 + wid * 2 + it;
        const int lab = labels[r];
        const int P   = gcnt[lab] - 1;
        const int tp2 = (r >> 8) * 2;         // first valid tj2 for this row

        float2 ev = *(const float2*)(emb  + (size_t)r   * DIMK + lane * 2);
        float2 gv = *(const float2*)(gsum + (size_t)lab * DIMK + lane * 2);
        float b0 = bf2f(f2bf_rne(ev.x));      // identical to an Ebf read
        float b1 = bf2f(f2bf_rne(ev.y));

        float dotg = ev.x * gv.x + ev.y * gv.y;
        float ssd  = ev.x * ev.x + ev.y * ev.y;
        float sdbf = b0 * b0 + b1 * b1;
        float Z = 0.f;
        if (lane >= tp2) Z = zpartR[(size_t)r * 64 + lane];

#pragma unroll
        for (int m = 1; m <= 32; m <<= 1) {
            dotg += __shfl_xor(dotg, m, 64);
            ssd  += __shfl_xor(ssd,  m, 64);
            sdbf += __shfl_xor(sdbf, m, 64);
            Z    += __shfl_xor(Z,    m, 64);
        }
        Z += zcol[r];                                                // below-diag cols
        Z -= __builtin_amdgcn_exp2f(__builtin_fmaf(sdbf, K1, -K2));  // remove diagonal

        const bool has = (P > 0);
        wsum += has ? ((dotg - ssd) * INV_T / (float)P - MSUB - __logf(Z)) : 0.f;
        wcnt += has ? 1 : 0;
    }

    if (lane == 0) { sf[wid] = wsum; si[wid] = wcnt; }
    __syncthreads();
    if (threadIdx.x == 0) {
        float bs = sf[0] + sf[1] + sf[2] + sf[3];
        int   bc = si[0] + si[1] + si[2] + si[3];
        atomicAdd(gtot, bs);                      // device-scope, memory-side
        atomicAdd(gcntT, bc);
        // Order the two adds' completion before the ticket RMW. Wave-local
        // wait on the outstanding VMEM acks — NOT a cross-XCD writeback.
        asm volatile("s_waitcnt vmcnt(0)" ::: "memory");
        int old = atomicAdd(ticket, 1);
        if (old == (int)gridDim.x - 1) {
            // All blocks' adds precede their ticket RMWs (each ordered by its
            // own vmcnt(0)); ticket==grid-1 implies all adds are globally
            // visible. Atomic reads are coherent regardless of local L2 state.
            float tot = atomicAdd(gtot, 0.0f);
            int   cc  = atomicAdd(gcntT, 0);
            out[0] = -tot / (float)(cc > 0 ? cc : 1);
        }
    }
}

extern "C" void kernel_launch(void* const* d_in, const int* in_sizes, int n_in,
                              void* d_out, int out_size, void* d_ws, size_t ws_size,
                              hipStream_t stream) {
    const float* emb  = (const float*)d_in[0];
    const int* labels = (const int*)d_in[1];
    float* out        = (float*)d_out;

    char* ws = (char*)d_ws;
    ushort* Ebf    = (ushort*)ws;                         // 2 MB  (8192*128*2)
    float*  zpartR = (float*)(ws + (2u << 20));           // 2 MB  ([8192][64] f32)
    float*  zcol   = (float*)(ws + (4u << 20));           // 32 KB (8192*4)
    float*  gsum   = (float*)(ws + (5u << 20));           // 1 MB  (2048*128*4)
    int*    gcnt   = (int*)  (ws + (6u << 20));           // 8 KB
    float*  gtot   = (float*)(ws + (6u << 20) + 8192);    // 4 B
    int*    gcntT  = (int*)  (ws + (6u << 20) + 8256);    // 4 B
    int*    ticket = (int*)  (ws + (6u << 20) + 8320);    // 4 B

    prep_kernel<<<1024, 256, 0, stream>>>(emb, Ebf, (float4*)zcol,
                                          gtot, gcntT, ticket);
    contrastive_main<<<1312, 512, 0, stream>>>(Ebf, zpartR, zcol,
                                               emb, labels, gsum, gcnt);
    finalize1<<<1024, 256, 0, stream>>>(emb, labels, gsum, gcnt, zpartR, zcol,
                                        gtot, gcntT, ticket, out);
}

// Round 12
// 91.798 us; speedup vs baseline: 1.1743x; 1.1743x over previous
//
#include <hip/hip_runtime.h>

// ContrastiveLoss on MI355X (gfx950), B=8192, D=128, labels in [0,2048).
// loss = -(1/cnt) sum_{i: P_i>0} [ S_i/P_i - M - ln Z_i ]
//   Z_i = sum_{j != i} exp(sim_ij - M),  sim = E E^T / T,  M = 1/T (valid shift).
//   S_i = (e_i . g_{lab_i} - e_i . e_i) / T  with fp32 class sums g_c.
//   P_i = count[lab_i] - 1.
// R23: restore R21 (91.2us, session best) after R22's atomic-ticket tail
//      regressed +16.6us. THREE tail-fusion attempts all lost (R14 fence
//      ticket +9, R13 cooperative finale, R22 atomic ticket +16): a separate
//      2us finalize2 launch beats any in-kernel cross-block finale. Tail
//      space closed. One riskless tweak: prep grid 1024->512 blocks
//      (2 float4/thread) — halves dispatch ramp on a ~1us-payload kernel.
// Budget model (R13 isolation + rocprof ordinals): each timed iteration
//      carries a 41us 256MB workspace-poison fill (harness-owned) + ~10us
//      launch/gaps + kernels {main ~25, prep ~5, fin1 ~4, fin2 ~2}.
// Frozen ledger: main untouched (5 falsified restructurings R12/15/16/19/20);
//      R17 8-wave 256x128 tile body (staged B, XOR LDS layout, 0 conflicts
//      measured, 16x16x32 MFMA, 32 waves/CU cap); R18 XCD bijective swizzle +
//      class-sum fused as main blocks [1056,1312) + zpartR[row][tj2]
//      transposed; R21 fin1 TLP x2 (1024 blk x 2 rows/wave) + inline sdbf;
//      bf16 Ebf intermediate is L2-residency-critical (R19: fp32 = +10us);
//      VGPR <=64 in main (R16/R20 occupancy step); plain launch_bounds
//      (R3/R7/R10); no zpartR pre-zero (fin1 masks lane >= 2*(r>>8)).

#define BATCH 8192
#define DIMK  128
#define INV_T 14.285714285714286f
#define MSUB  14.285714285714286f
#define K1    20.609929155311264f   // INV_T * log2(e)
#define K2    20.609929155311264f   // MSUB  * log2(e)

typedef short bf16x8 __attribute__((ext_vector_type(8)));
typedef float f32x4  __attribute__((ext_vector_type(4)));

__device__ __forceinline__ unsigned short f2bf_rne(float f) {
    unsigned u = __float_as_uint(f);
    u += 0x7FFFu + ((u >> 16) & 1u);
    return (unsigned short)(u >> 16);
}
__device__ __forceinline__ float bf2f(unsigned short b) {
    return __uint_as_float(((unsigned)b) << 16);
}

// ---------------------------------------------------------------------------
// Prep: 512 blocks x 256: fp32->bf16 cvt (2 float4/thread, grid-strided)
//       + zero zcol (32 KB). Payload ~6MB => ramp-dominated; fewer blocks
//       = shorter dispatch ramp.
__global__ __launch_bounds__(256) void
prep_kernel(const float* __restrict__ emb, ushort* __restrict__ Ebf,
            float4* __restrict__ zcol4) {
    int i = blockIdx.x * 256 + threadIdx.x;
    if (i < 2048) {                           // zcol: 8192 floats = 2048 float4
        float4 z = {0.f, 0.f, 0.f, 0.f};
        zcol4[i] = z;
    }
#pragma unroll
    for (int k = 0; k < 2; ++k) {
        int j = i + k * 131072;
        float4 v = ((const float4*)emb)[j];
        ushort4 o;
        o.x = f2bf_rne(v.x); o.y = f2bf_rne(v.y);
        o.z = f2bf_rne(v.z); o.w = f2bf_rne(v.w);
        ((ushort4*)Ebf)[j] = o;
    }
}

// ---------------------------------------------------------------------------
// Main (FROZEN, R21): blocks [0,1056): Z partials over the upper triangle;
// blocks [1056,1312): class sums (8 classes/block, overlapping the tile
// window). Tile blocks: 1056 = 528 macro-tiles x 2 col-halves, 512 threads
// (8 waves), XCD-swizzled. Macro-tile (ti,tj), tj>=ti; block covers rows
// [ti*256,+256) x cols [tj*256+ch*128,+128). B staged once (32 KB),
// conflict-free XOR layout (measured 0 conflicts):
// chunk (col,c) -> unit (col>>4)*256 + c*16 + ((col&15)^c). Wave owns 32
// rows (afrag[2][4]); single 4-deep MFMA chain per mt (VGPR<=64).
// Row partials -> zpartR[row][tj2] (tj2 = tj*2+ch). Col partials (off-diag
// only) -> cpart LDS combine -> atomicAdd zcol[col].
__global__ __launch_bounds__(512) void
contrastive_main(const ushort* __restrict__ Ebf, float* __restrict__ zpartR,
                 float* __restrict__ zcol, const float* __restrict__ emb,
                 const int* __restrict__ labels, float* __restrict__ gsum,
                 int* __restrict__ gcnt) {
    __shared__ __align__(16) ushort Bs[2048 * 8];     // 32 KB (2048 16B units)
    __shared__ float cpart[8][128];                   // 4 KB
    const int tid  = threadIdx.x;
    const int lane = tid & 63;
    const int wid  = tid >> 6;                        // 0..7
    const int quad = lane >> 4;
    const int l16  = lane & 15;

    if (blockIdx.x >= 1056) {
        // ---- class sums: 256 blocks x 8 waves, 1 class per wave ----
        int* labs = (int*)&Bs[0];                     // alias the 32 KB region
#pragma unroll
        for (int it = 0; it < 4; ++it)
            ((int4*)labs)[it * 512 + tid] = ((const int4*)labels)[it * 512 + tid];
        __syncthreads();

        const int c = (blockIdx.x - 1056) * 8 + wid;  // class id [0,2048)
        float2 acc = {0.f, 0.f};
        int cnt = 0;
        int nl = labs[lane];
        for (int j0 = 0; j0 < BATCH; j0 += 64) {
            int cur = nl;
            int nidx = j0 + 64 < BATCH ? j0 + 64 : 0;
            nl = labs[nidx + lane];
            unsigned long long m = __ballot(cur == c);
            cnt += __popcll(m);
            while (m) {
                int j = __ffsll(m) - 1;
                m &= m - 1;
                float2 v = *(const float2*)(emb + (size_t)(j0 + j) * DIMK + lane * 2);
                acc.x += v.x; acc.y += v.y;
            }
        }
        *(float2*)(gsum + (size_t)c * DIMK + lane * 2) = acc;
        if (lane == 0) gcnt[c] = cnt;
        return;
    }

    // ---- tile path ----
    // XCD-aware bijective swizzle: 1056 = 8 * 132; (bid&7) == XCD gets the
    // contiguous tt range [x*132, x*132+132).
    const int bid = blockIdx.x;
    const int tt  = (bid & 7) * 132 + (bid >> 3);

    // tt -> (ti, tj, ch)
    int b = tt >> 1;
    const int ch = tt & 1;
    int ti = 0;
    while (b >= 32 - ti) { b -= 32 - ti; ++ti; }
    const int tj  = ti + b;
    const int tj2 = tj * 2 + ch;
    const int row_base = ti * 256 + wid * 32;
    const int col_base = tj * 256 + ch * 128;

    // A-fragments for this wave's 32 rows (register-resident), from L2.
    bf16x8 afrag[2][4];
#pragma unroll
    for (int mt = 0; mt < 2; ++mt)
#pragma unroll
        for (int kk = 0; kk < 4; ++kk)
            afrag[mt][kk] = *(const bf16x8*)(Ebf + (size_t)(row_base + mt * 16 + l16) * DIMK
                                             + kk * 32 + quad * 8);

    // Stage 128 cols: 2048 16B chunks; thread t handles chunk f = it*512+t:
    // col = f>>4, c = f&15; global read coalesced (16 lanes = 256B of one col);
    // LDS write at swizzled unit (col>>4)*256 + c*16 + ((col&15)^c).
#pragma unroll
    for (int it = 0; it < 4; ++it) {
        int f   = it * 512 + tid;
        int col = f >> 4;
        int c   = f & 15;
        uint4 v = *(const uint4*)(Ebf + (size_t)(col_base + col) * DIMK + c * 8);
        *(uint4*)&Bs[((col >> 4) * 256 + c * 16 + ((col & 15) ^ c)) * 8] = v;
    }
    __syncthreads();

    float zacc[8];
#pragma unroll
    for (int s = 0; s < 8; ++s) zacc[s] = 0.f;

    for (int nt = 0; nt < 8; ++nt) {
        bf16x8 bfrag[4];
#pragma unroll
        for (int kk = 0; kk < 4; ++kk) {
            const int c2 = kk * 4 + quad;
            bfrag[kk] = *(const bf16x8*)&Bs[(nt * 256 + c2 * 16 + (l16 ^ c2)) * 8];
        }

        float csum = 0.f;
#pragma unroll
        for (int mt = 0; mt < 2; ++mt) {
            f32x4 c = {0.f, 0.f, 0.f, 0.f};
#pragma unroll
            for (int kk = 0; kk < 4; ++kk)
                c = __builtin_amdgcn_mfma_f32_16x16x32_bf16(afrag[mt][kk], bfrag[kk], c, 0, 0, 0);
#pragma unroll
            for (int r = 0; r < 4; ++r) {
                float e = __builtin_amdgcn_exp2f(__builtin_fmaf(c[r], K1, -K2));
                zacc[mt * 4 + r] += e;
                csum += e;
            }
        }
        // col partial for col (nt*16 + l16) over this wave's 32 rows
        csum += __shfl_xor(csum, 16, 64);
        csum += __shfl_xor(csum, 32, 64);
        if (quad == 0) cpart[wid][nt * 16 + l16] = csum;
    }

    // Row partials: reduce each row-slot over the 16 lanes sharing the row;
    // store transposed: zpartR[row][tj2] (fin1 reads 256B/row coalesced).
#pragma unroll
    for (int s = 0; s < 8; ++s) {
        float z = zacc[s];
#pragma unroll
        for (int m = 1; m <= 8; m <<= 1) z += __shfl_xor(z, m, 64);
        if (l16 == 0) {
            int row = row_base + (s >> 2) * 16 + quad * 4 + (s & 3);
            zpartR[(size_t)row * 64 + tj2] = z;
        }
    }

    // Col partials: combine the 8 waves, one distributed atomic per column.
    __syncthreads();
    if (ti != tj && tid < 128) {
        float s = cpart[0][tid] + cpart[1][tid] + cpart[2][tid] + cpart[3][tid]
                + cpart[4][tid] + cpart[5][tid] + cpart[6][tid] + cpart[7][tid];
        atomicAdd(&zcol[col_base + tid], s);
    }
}

// ---------------------------------------------------------------------------
// Finalize 1 (R21): 1024 blocks x 256 (4 waves); each wave processes 2 rows.
// Per row: lane l covers dims 2l,2l+1; Z gather is zpartR[r][lane] — 256B
// contiguous (written only for tj2 >= 2*(r>>8): mask, no pre-zeroing);
// zcol[r] added after the butterfly; bf16 self-dot recomputed inline.
__global__ __launch_bounds__(256) void
finalize1(const float* __restrict__ emb, const int* __restrict__ labels,
          const float* __restrict__ gsum, const int* __restrict__ gcnt,
          const float* __restrict__ zpartR, const float* __restrict__ zcol,
          float* __restrict__ bpart, int* __restrict__ bcnt) {
    __shared__ float sf[4];
    __shared__ int   si[4];
    const int lane = threadIdx.x & 63;
    const int wid  = threadIdx.x >> 6;

    float wsum = 0.f;
    int   wcnt = 0;
#pragma unroll
    for (int it = 0; it < 2; ++it) {
        const int r   = blockIdx.x * 8 + wid * 2 + it;
        const int lab = labels[r];
        const int P   = gcnt[lab] - 1;
        const int tp2 = (r >> 8) * 2;         // first valid tj2 for this row

        float2 ev = *(const float2*)(emb  + (size_t)r   * DIMK + lane * 2);
        float2 gv = *(const float2*)(gsum + (size_t)lab * DIMK + lane * 2);
        float b0 = bf2f(f2bf_rne(ev.x));      // identical to an Ebf read
        float b1 = bf2f(f2bf_rne(ev.y));

        float dotg = ev.x * gv.x + ev.y * gv.y;
        float ssd  = ev.x * ev.x + ev.y * ev.y;
        float sdbf = b0 * b0 + b1 * b1;
        float Z = 0.f;
        if (lane >= tp2) Z = zpartR[(size_t)r * 64 + lane];

#pragma unroll
        for (int m = 1; m <= 32; m <<= 1) {
            dotg += __shfl_xor(dotg, m, 64);
            ssd  += __shfl_xor(ssd,  m, 64);
            sdbf += __shfl_xor(sdbf, m, 64);
            Z    += __shfl_xor(Z,    m, 64);
        }
        Z += zcol[r];                                                // below-diag cols
        Z -= __builtin_amdgcn_exp2f(__builtin_fmaf(sdbf, K1, -K2));  // remove diagonal

        const bool has = (P > 0);
        wsum += has ? ((dotg - ssd) * INV_T / (float)P - MSUB - __logf(Z)) : 0.f;
        wcnt += has ? 1 : 0;
    }

    if (lane == 0) { sf[wid] = wsum; si[wid] = wcnt; }
    __syncthreads();
    if (threadIdx.x == 0) {
        bpart[blockIdx.x] = sf[0] + sf[1] + sf[2] + sf[3];
        bcnt [blockIdx.x] = si[0] + si[1] + si[2] + si[3];
    }
}

// ---------------------------------------------------------------------------
// Finalize 2: reduce 1024 block partials -> scalar loss. 1 block x 256.
__global__ __launch_bounds__(256) void
finalize2(const float* __restrict__ bpart, const int* __restrict__ bcnt,
          float* __restrict__ out) {
    __shared__ float sf[4];
    __shared__ int   si[4];
    const int t = threadIdx.x;
    float v = 0.f; int c = 0;
#pragma unroll
    for (int k = 0; k < 4; ++k) {
        v += bpart[t + k * 256];
        c += bcnt [t + k * 256];
    }
#pragma unroll
    for (int m = 1; m <= 32; m <<= 1) {
        v += __shfl_xor(v, m, 64);
        c += __shfl_xor(c, m, 64);
    }
    if ((t & 63) == 0) { sf[t >> 6] = v; si[t >> 6] = c; }
    __syncthreads();
    if (t == 0) {
        float tot = sf[0] + sf[1] + sf[2] + sf[3];
        int cc = si[0] + si[1] + si[2] + si[3];
        out[0] = -tot / (float)(cc > 0 ? cc : 1);
    }
}

extern "C" void kernel_launch(void* const* d_in, const int* in_sizes, int n_in,
                              void* d_out, int out_size, void* d_ws, size_t ws_size,
                              hipStream_t stream) {
    const float* emb  = (const float*)d_in[0];
    const int* labels = (const int*)d_in[1];
    float* out        = (float*)d_out;

    char* ws = (char*)d_ws;
    ushort* Ebf    = (ushort*)ws;                         // 2 MB  (8192*128*2)
    float*  zpartR = (float*)(ws + (2u << 20));           // 2 MB  ([8192][64] f32)
    float*  zcol   = (float*)(ws + (4u << 20));           // 32 KB (8192*4)
    float*  gsum   = (float*)(ws + (5u << 20));           // 1 MB  (2048*128*4)
    int*    gcnt   = (int*)  (ws + (6u << 20));           // 8 KB
    float*  bpart  = (float*)(ws + (6u << 20) + 8192);    // 4 KB  (1024 f32)
    int*    bcnt   = (int*)  (ws + (6u << 20) + 16384);   // 4 KB  (1024 i32)

    prep_kernel<<<512, 256, 0, stream>>>(emb, Ebf, (float4*)zcol);
    contrastive_main<<<1312, 512, 0, stream>>>(Ebf, zpartR, zcol,
                                               emb, labels, gsum, gcnt);
    finalize1<<<1024, 256, 0, stream>>>(emb, labels, gsum, gcnt, zpartR, zcol,
                                        bpart, bcnt);
    finalize2<<<1, 256, 0, stream>>>(bpart, bcnt, out);
}